// Round 9
// baseline (248.267 us; speedup 1.0000x reference)
//
#include <hip/hip_runtime.h>
#include <cmath>

// PairList forward: n atoms, P = n(n-1)/2 pairs in triu(k=1) row-major order.
// Output (float32, concatenated flat, 7P elements):
//   [0,P)   pair row0: i or -1        [P,2P)  pair row1: j or -1
//   [2P,3P) d_ij*valid                [3P,6P) r_ij*valid (P,3 row-major)
//   [6P,7P) valid as 0/1
// valid = (sub[i]==sub[j]) && (|pos[j]-pos[i]| < 5).
//
// (tile,row) 2D grid: i = blockIdx.y is block-uniform -> NO per-thread
// triangular inversion (rounds 3-8 showed the sqrt+fixup chain costs ~30us),
// no LDS, no barriers. Row-local pair index local = bx*1024 + tid*4 - (T(i)&3)
// keeps p = T(i)+local 16B-aligned for float4 stores. Subsystem validity is a
// block-uniform scalar binary search (j < re), so hot-path threads issue only
// constants + 7 contiguous float4 stores. Head/tail partial groups (<=2/row)
// take a masked scalar path. Cached stores only (nt => 2.3x write amp, r6).

__global__ __launch_bounds__(256) void pairlist_rows(
    const float* __restrict__ pos, const int* __restrict__ sub,
    float* __restrict__ out, int n, long long P) {
  const int i = blockIdx.y;                      // row, 0..n-2
  const int L = n - 1 - i;                       // pairs in this row
  const long long Ti = (long long)i * (2LL * n - i - 1) / 2;
  const int a = (int)(Ti & 3);                   // alignment shift
  const int local0 = (int)(blockIdx.x * 1024 + threadIdx.x * 4) - a;
  if (local0 >= L) return;                       // empty tile / beyond row

  // Block-uniform run end for row i (sorted subsystem ids).
  const int shift = (sub[n - 1] == 0) ? 1 : 0;   // int64 words vs int32
  const int s = sub[i << shift];
  int lo = i + 1, hi = n;
  while (lo < hi) {
    int mid = (lo + hi) >> 1;
    if (sub[mid << shift] > s) hi = mid; else lo = mid + 1;
  }
  const int vLen = lo - (i + 1);                 // local < vLen -> same subsys

  float* oi  = out;
  float* oj  = out + P;
  float* od  = out + 2 * P;
  float* orr = out + 3 * P;
  float* ov  = out + 6 * P;

  const long long p0 = Ti + local0;              // p0 % 4 == 0 when local0>=0

  // Fast path: full 4-group inside row, entirely cross-subsystem.
  if (local0 >= vLen && local0 >= 0 && local0 + 4 <= L) {
    const float4 NEG = make_float4(-1.f, -1.f, -1.f, -1.f);
    const float4 ZER = make_float4(0.f, 0.f, 0.f, 0.f);
    *reinterpret_cast<float4*>(oi + p0) = NEG;
    *reinterpret_cast<float4*>(oj + p0) = NEG;
    *reinterpret_cast<float4*>(od + p0) = ZER;
    *reinterpret_cast<float4*>(ov + p0) = ZER;
    float4* rb = reinterpret_cast<float4*>(orr + 3 * p0);
    rb[0] = ZER; rb[1] = ZER; rb[2] = ZER;
    return;
  }

  // General path (valid region + row head/tail partial groups).
  const float pix = pos[3 * i], piy = pos[3 * i + 1], piz = pos[3 * i + 2];
  float fi[4], fj[4], fd[4], fv[4], fr[12];

#pragma unroll
  for (int k = 0; k < 4; ++k) {
    const int local = local0 + k;
    float vi = -1.f, vj = -1.f, vd = 0.f, vv = 0.f;
    float rx = 0.f, ry = 0.f, rz = 0.f;
    if (local >= 0 && local < vLen) {            // same-subsystem pair
      const int j = i + 1 + local;
      const float dx = pos[3 * j]     - pix;
      const float dy = pos[3 * j + 1] - piy;
      const float dz = pos[3 * j + 2] - piz;
      const float dd = sqrtf(dx * dx + dy * dy + dz * dz);
      if (dd < 5.f) {
        vi = (float)i; vj = (float)j; vd = dd; vv = 1.f;
        rx = dx; ry = dy; rz = dz;
      }
    }
    fi[k] = vi; fj[k] = vj; fd[k] = vd; fv[k] = vv;
    fr[3 * k] = rx; fr[3 * k + 1] = ry; fr[3 * k + 2] = rz;
  }

  if (local0 >= 0 && local0 + 4 <= L) {          // aligned full group
    *reinterpret_cast<float4*>(oi + p0) = make_float4(fi[0], fi[1], fi[2], fi[3]);
    *reinterpret_cast<float4*>(oj + p0) = make_float4(fj[0], fj[1], fj[2], fj[3]);
    *reinterpret_cast<float4*>(od + p0) = make_float4(fd[0], fd[1], fd[2], fd[3]);
    *reinterpret_cast<float4*>(ov + p0) = make_float4(fv[0], fv[1], fv[2], fv[3]);
    float4* rb = reinterpret_cast<float4*>(orr + 3 * p0);
    rb[0] = make_float4(fr[0], fr[1], fr[2],  fr[3]);
    rb[1] = make_float4(fr[4], fr[5], fr[6],  fr[7]);
    rb[2] = make_float4(fr[8], fr[9], fr[10], fr[11]);
  } else {                                       // row head/tail: masked scalar
    for (int k = 0; k < 4; ++k) {
      const int local = local0 + k;
      if (local < 0 || local >= L) continue;
      const long long p = Ti + local;
      oi[p] = fi[k]; oj[p] = fj[k]; od[p] = fd[k]; ov[p] = fv[k];
      orr[3 * p] = fr[3 * k]; orr[3 * p + 1] = fr[3 * k + 1];
      orr[3 * p + 2] = fr[3 * k + 2];
    }
  }
}

extern "C" void kernel_launch(void* const* d_in, const int* in_sizes, int n_in,
                              void* d_out, int out_size, void* d_ws, size_t ws_size,
                              hipStream_t stream) {
  const float* pos = (const float*)d_in[0];
  const int*   sub = (const int*)d_in[1];
  float* out = (float*)d_out;

  // Geometry from out_size: out_size = 7P, P = n(n-1)/2.
  long long P = (long long)out_size / 7;
  int n = (int)((1.0 + sqrt(1.0 + 8.0 * (double)P)) * 0.5 + 0.5);
  if ((long long)n * (n - 1) / 2 != P) {        // fallback
    n = in_sizes[0] / 3;
    P = (long long)n * (n - 1) / 2;
  }

  // Tiles must cover locals up to (L-1)+a <= n-2+3: NT = ceil((n+2)/1024)+pad.
  int NT = (int)((n + 1025) / 1024);
  hipLaunchKernelGGL(pairlist_rows, dim3(NT, n - 1), dim3(256), 0, stream,
                     pos, sub, out, n, P);
}

// Round 10
// 224.333 us; speedup vs baseline: 1.1067x; 1.1067x over previous
//
#include <hip/hip_runtime.h>
#include <cmath>

// PairList forward: n atoms, P = n(n-1)/2 pairs in triu(k=1) row-major order.
// Output (float32, concatenated flat, 7P elements):
//   [0,P)   pair row0: i or -1        [P,2P)  pair row1: j or -1
//   [2P,3P) d_ij*valid                [3P,6P) r_ij*valid (P,3 row-major)
//   [6P,7P) valid as 0/1
// valid = (sub[i]==sub[j]) && (|pos[j]-pos[i]| < 5).
//
// Three-kernel structure exploiting sorted subsystem ids (same-subsystem
// candidates of row i are a CONTIGUOUS PREFIX of the row, ~1.5% of all pairs):
//   1) fill NEG over [0,2P)   -- pure branch-free grid-stride float4 fill
//   2) fill ZER over [2P,7P)  -- ditto (both mimic the 6.8 TB/s rocclr fill)
//   3) prefix overwrite: one block per row; block-uniform binary search for
//      vLen; threads write the 7 output slots for prefix pairs (~14.5 MB).
// No nontemporal stores (2.3x write amplification, round 6). No per-thread
// triangular inversion (30+ us, rounds 7-9). No ballot scatter (round 4).

__global__ __launch_bounds__(256) void fill_f4(float4* __restrict__ dst,
                                               long long nq, float v) {
  long long g = (long long)blockIdx.x * blockDim.x + threadIdx.x;
  const long long stride = (long long)gridDim.x * blockDim.x;
  const float4 val = make_float4(v, v, v, v);
  for (long long q = g; q < nq; q += stride) dst[q] = val;
}

__global__ __launch_bounds__(256) void fill_scalar(float* __restrict__ dst,
                                                   long long cnt, float v) {
  long long g = (long long)blockIdx.x * blockDim.x + threadIdx.x;
  const long long stride = (long long)gridDim.x * blockDim.x;
  for (long long q = g; q < cnt; q += stride) dst[q] = v;
}

__global__ __launch_bounds__(256) void prefix_kernel(
    const float* __restrict__ pos, const int* __restrict__ sub,
    float* __restrict__ out, int n, long long P) {
  const int i = blockIdx.x;                      // row, 0..n-2
  const int shift = (sub[n - 1] == 0) ? 1 : 0;   // int64 words vs int32
  const int s = sub[i << shift];
  int lo = i + 1, hi = n;                        // first idx>i with sub>s
  while (lo < hi) {
    int mid = (lo + hi) >> 1;
    if (sub[mid << shift] > s) hi = mid; else lo = mid + 1;
  }
  const int vLen = lo - (i + 1);                 // same-subsystem prefix length
  if (vLen <= 0) return;

  const long long Ti = (long long)i * (2LL * n - i - 1) / 2;
  const float pix = pos[3 * i], piy = pos[3 * i + 1], piz = pos[3 * i + 2];

  float* oi  = out;
  float* oj  = out + P;
  float* od  = out + 2 * P;
  float* orr = out + 3 * P;
  float* ov  = out + 6 * P;

  for (int local = threadIdx.x; local < vLen; local += blockDim.x) {
    const int j = i + 1 + local;
    const float dx = pos[3 * j]     - pix;
    const float dy = pos[3 * j + 1] - piy;
    const float dz = pos[3 * j + 2] - piz;
    const float dd = sqrtf(dx * dx + dy * dy + dz * dz);
    const bool valid = dd < 5.0f;
    const long long p = Ti + local;
    oi[p] = valid ? (float)i : -1.0f;
    oj[p] = valid ? (float)j : -1.0f;
    od[p] = valid ? dd : 0.0f;
    orr[3 * p]     = valid ? dx : 0.0f;
    orr[3 * p + 1] = valid ? dy : 0.0f;
    orr[3 * p + 2] = valid ? dz : 0.0f;
    ov[p] = valid ? 1.0f : 0.0f;
  }
}

extern "C" void kernel_launch(void* const* d_in, const int* in_sizes, int n_in,
                              void* d_out, int out_size, void* d_ws, size_t ws_size,
                              hipStream_t stream) {
  const float* pos = (const float*)d_in[0];
  const int*   sub = (const int*)d_in[1];
  float* out = (float*)d_out;

  // Geometry from out_size: out_size = 7P, P = n(n-1)/2.
  long long P = (long long)out_size / 7;
  int n = (int)((1.0 + sqrt(1.0 + 8.0 * (double)P)) * 0.5 + 0.5);
  if ((long long)n * (n - 1) / 2 != P) {        // fallback
    n = in_sizes[0] / 3;
    P = (long long)n * (n - 1) / 2;
  }

  const long long negCnt = 2 * P;               // [0,2P) <- -1.0
  const long long zerCnt = 5 * P;               // [2P,7P) <- 0.0

  if ((negCnt & 3) == 0) {   // 16B-aligned split (true for n=8192)
    hipLaunchKernelGGL(fill_f4, dim3(8192), dim3(256), 0, stream,
                       (float4*)out, negCnt / 4, -1.0f);
    hipLaunchKernelGGL(fill_f4, dim3(8192), dim3(256), 0, stream,
                       (float4*)(out + negCnt), zerCnt / 4, 0.0f);
  } else {                   // robustness fallback: scalar fills
    hipLaunchKernelGGL(fill_scalar, dim3(8192), dim3(256), 0, stream,
                       out, negCnt, -1.0f);
    hipLaunchKernelGGL(fill_scalar, dim3(8192), dim3(256), 0, stream,
                       out + negCnt, zerCnt, 0.0f);
  }

  hipLaunchKernelGGL(prefix_kernel, dim3(n - 1), dim3(256), 0, stream,
                     pos, sub, out, n, P);
}